// Round 1
// 115.257 us; speedup vs baseline: 1.0888x; 1.0888x over previous
//
#include <hip/hip_runtime.h>

// QTT 3D sampling, round 10: barrier-free per-wave K-split GEMM bodies.
//   K1 (577 blocks):
//     block 0      : counting sort of samples by d4 (perms/bases)
//     blocks 1-64  : T[d5,d6,d7] = C5·(C6·C7)          (512 x 256 table)
//     blocks 65-576: P3[d0,d1,d2,d3] = C0·C1·C2·C3     (4096 x 256 table)
//                    block = (d0,d2,d3); 8 rows (d1) built in-LDS from
//                    C0/C1/C2, then K=256 GEMM vs C3[d3].
//                    NEW: wave w owns K in [64w,64w+64) with a PRIVATE
//                    double-buffered B stage (counted vmcnt(4), no
//                    __syncthreads in the main loop); 4-way cross-wave
//                    K-reduction through the dead Bs region at the end.
//   K2 (512 blocks): V4 = gather(P3, prefix4) x C4[d4] (d4-grouped GEMM,
//                    same barrier-free K-split), fused epilogue
//                    out[i] = dot(V4row, T[suffix3]).
// Core shapes: (r_l, 8, r_{l+1}), ranks 1,8,64,256,256,256,64,8,1.
// C_l[k][d][s] at C_l[k*8*r_out + d*r_out + s].

typedef unsigned int u32;

__device__ __forceinline__ void async_load16(const float* g, float* l) {
    __builtin_amdgcn_global_load_lds(
        (const __attribute__((address_space(1))) u32*)g,
        (__attribute__((address_space(3))) u32*)l, 16, 0, 0);
}
__device__ __forceinline__ void fma4(float4& c, float a, const float4& b) {
    c.x = fmaf(a, b.x, c.x); c.y = fmaf(a, b.y, c.y);
    c.z = fmaf(a, b.z, c.z); c.w = fmaf(a, b.w, c.w);
}
__device__ __forceinline__ int digit_of(int x, int y, int z, int sh) {
    return 4*((x>>sh)&1) + 2*((y>>sh)&1) + ((z>>sh)&1);
}

// ---------------- K1: prep + T table + dense P3 table ------------------------
__global__ __launch_bounds__(256, 3) void tables_kernel(
    const float* __restrict__ C0, const float* __restrict__ C1,
    const float* __restrict__ C2, const float* __restrict__ C3,
    const float* __restrict__ C5, const float* __restrict__ C6,
    const float* __restrict__ C7,
    const int* __restrict__ coords, int n,
    int* __restrict__ perms, int* __restrict__ bases,
    float* __restrict__ P3, float* __restrict__ T)
{
    __shared__ __align__(16) union {
        struct { unsigned char digs[8192]; int cnt[8]; int offs[8]; } p;
        struct { float S6s[8][64]; } b;
        struct { float v64[8][64]; float As[8][260]; float Bs[4][2][4][256]; } g;
    } u;
    const int t = threadIdx.x;
    const int ln = t & 63, wv = t >> 6;
    const int bx = blockIdx.x;

    if (bx == 0) {
        // ---- prep: counting sort by d4 (sh 3) ----
        if (t < 8) u.p.cnt[t] = 0;
        __syncthreads();
        for (int i = t; i < n; i += 256) {
            const int d = digit_of(coords[3*i], coords[3*i+1], coords[3*i+2], 3);
            u.p.digs[i] = (unsigned char)d;
            atomicAdd(&u.p.cnt[d], 1);
        }
        __syncthreads();
        if (t == 0) {
            int run = 0;
            for (int d = 0; d < 8; ++d) {
                u.p.offs[d] = run;
                bases[d] = run;
                run += u.p.cnt[d];
            }
            bases[8] = run;
        }
        __syncthreads();
        for (int i = t; i < n; i += 256) {
            const int pos = atomicAdd(&u.p.offs[u.p.digs[i]], 1);
            perms[pos] = i;
        }
    } else if (bx < 65) {
        // ---- T table: block = (d5, d6), all 8 d7 ----
        const int bb = bx - 1;
        const int d5 = bb >> 3, d6 = bb & 7;
#pragma unroll
        for (int j = 0; j < 2; ++j) {
            const int idx = t + 256*j, d7 = idx >> 6, s = idx & 63;
            float acc = 0.f;
#pragma unroll
            for (int jj = 0; jj < 8; ++jj)
                acc = fmaf(C6[s*64 + d6*8 + jj], C7[jj*8 + d7], acc);
            u.b.S6s[d7][s] = acc;
        }
        __syncthreads();
        float4 creg[16];
#pragma unroll
        for (int s4 = 0; s4 < 16; ++s4)
            creg[s4] = *(const float4*)(C5 + (size_t)t*512 + d5*64 + s4*4);
#pragma unroll 1
        for (int d7 = 0; d7 < 8; ++d7) {
            float acc = 0.f;
#pragma unroll
            for (int s4 = 0; s4 < 16; ++s4) {
                const float4 a = creg[s4];
                const float4 b = *(const float4*)&u.b.S6s[d7][s4*4];
                acc = fmaf(a.x, b.x, acc); acc = fmaf(a.y, b.y, acc);
                acc = fmaf(a.z, b.z, acc); acc = fmaf(a.w, b.w, acc);
            }
            T[(size_t)((d5*8 + d6)*8 + d7)*256 + t] = acc;
        }
    } else {
        // ---- P3 table: block = (d0, d2, d3); rows = 8 d1 values ----
        const int bb = bx - 65;
        const int d3 = bb & 7, d2 = (bb >> 3) & 7, d0 = bb >> 6;
        const float* Cd = C3 + d3 * 256;       // (k,c) at Cd[k*2048 + c]
        float* BsF = &u.g.Bs[0][0][0][0];
        const int kbase = wv * 64;             // this wave's K range

        // prefetch this wave's step-0 B rows (k = kbase..kbase+3)
#pragma unroll
        for (int j = 0; j < 4; ++j)
            async_load16(Cd + (size_t)(kbase + j)*2048 + ln*4,
                         &u.g.Bs[wv][0][j][ln*4]);

        // v64[d1][c] = sum_r C0[d0,r] * C1[r, d1, c]
#pragma unroll
        for (int j = 0; j < 2; ++j) {
            const int idx = t + 256*j, d1 = idx >> 6, c = idx & 63;
            float acc = 0.f;
#pragma unroll
            for (int r = 0; r < 8; ++r)
                acc = fmaf(C0[d0*8 + r], C1[r*512 + d1*64 + c], acc);
            u.g.v64[d1][c] = acc;
        }
        __syncthreads();

        // As[d1][k] = sum_j v64[d1][j] * C2[j, d2, k]; wave wv builds d1=wv*2+{0,1}
        {
            float4 accA0 = make_float4(0,0,0,0), accA1 = make_float4(0,0,0,0);
#pragma unroll 8
            for (int j = 0; j < 64; ++j) {
                const float4 c2 = *(const float4*)(C2 + (size_t)j*2048 + d2*256 + ln*4);
                fma4(accA0, u.g.v64[wv*2 + 0][j], c2);
                fma4(accA1, u.g.v64[wv*2 + 1][j], c2);
            }
            *(float4*)&u.g.As[wv*2 + 0][ln*4] = accA0;
            *(float4*)&u.g.As[wv*2 + 1][ln*4] = accA1;
        }
        __syncthreads();                       // As complete (also drains prefetch)

        // main GEMM: wave wv accumulates ALL 8 rows over k in [kbase, kbase+64)
        // private dbuf B stage, counted vmcnt, NO barriers.
        float4 acc[8];
#pragma unroll
        for (int r = 0; r < 8; ++r) acc[r] = make_float4(0,0,0,0);

#pragma unroll 1
        for (int s = 0; s < 16; ++s) {
            if (s < 15) {
                const int nb = (s + 1) & 1;
                const int ko = kbase + (s + 1) * 4;
#pragma unroll
                for (int j = 0; j < 4; ++j)
                    async_load16(Cd + (size_t)(ko + j)*2048 + ln*4,
                                 &u.g.Bs[wv][nb][j][ln*4]);
                asm volatile("s_waitcnt vmcnt(4)" ::: "memory");
            } else {
                asm volatile("s_waitcnt vmcnt(0)" ::: "memory");
            }
            __builtin_amdgcn_sched_barrier(0);
            const int cb = s & 1, kb = kbase + s * 4;
            const float4 b0v = *(const float4*)&u.g.Bs[wv][cb][0][ln*4];
            const float4 b1v = *(const float4*)&u.g.Bs[wv][cb][1][ln*4];
            const float4 b2v = *(const float4*)&u.g.Bs[wv][cb][2][ln*4];
            const float4 b3v = *(const float4*)&u.g.Bs[wv][cb][3][ln*4];
#pragma unroll
            for (int r = 0; r < 8; ++r) {
                const float4 a = *(const float4*)&u.g.As[r][kb];
                fma4(acc[r], a.x, b0v); fma4(acc[r], a.y, b1v);
                fma4(acc[r], a.z, b2v); fma4(acc[r], a.w, b3v);
            }
        }

        // cross-wave K reduction via (dead) Bs region: wave w owns 2048 floats
        {
            float* my = BsF + wv * 2048;
#pragma unroll
            for (int r = 0; r < 8; ++r)
                *(float4*)&my[r*256 + ln*4] = acc[r];
        }
        __syncthreads();
#pragma unroll
        for (int i = 0; i < 2; ++i) {
            const int r = wv*2 + i;            // r == d1
            float4 v = *(const float4*)&BsF[       r*256 + ln*4];
            const float4 p1 = *(const float4*)&BsF[2048 + r*256 + ln*4];
            const float4 p2 = *(const float4*)&BsF[4096 + r*256 + ln*4];
            const float4 p3 = *(const float4*)&BsF[6144 + r*256 + ln*4];
            v.x += p1.x + p2.x + p3.x; v.y += p1.y + p2.y + p3.y;
            v.z += p1.z + p2.z + p3.z; v.w += p1.w + p2.w + p3.w;
            const int ai = d0*512 + r*64 + d2*8 + d3;
            *(float4*)(P3 + (size_t)ai*256 + ln*4) = v;
        }
    }
}

// ---------------- K2: stage4 (gather P3, x C4[d4]) + fused final -------------
__global__ __launch_bounds__(256, 2) void stage4_final_kernel(
    const float* __restrict__ P3, const float* __restrict__ C4,
    const float* __restrict__ T, const int* __restrict__ coords,
    const int* __restrict__ perm, const int* __restrict__ base,
    float* __restrict__ out)
{
    const int d = blockIdx.x;
    const int b0 = base[d], b1 = base[d + 1];
    const int nrows = b1 - b0;
    const int t = threadIdx.x, ln = t & 63, wv = t >> 6;

    __shared__ __align__(16) float Arm[8][260];
    __shared__ __align__(16) float Bs[4][2][4][256];
    __shared__ int rows[8], aidx[8], qs[8];
    float* BsF = &Bs[0][0][0][0];

    const float* Cd = C4 + d * 256;
    const int kbase = wv * 64;

    for (int tile = blockIdx.y; tile * 8 < nrows; tile += (int)gridDim.y) {
        const int row0 = b0 + tile * 8;

        // prefetch this wave's step-0 B rows
#pragma unroll
        for (int j = 0; j < 4; ++j)
            async_load16(Cd + (size_t)(kbase + j)*2048 + ln*4,
                         &Bs[wv][0][j][ln*4]);

        if (t < 8) {
            const int gr = row0 + t;
            const int rr = (gr < b1) ? perm[gr] : -1;
            rows[t] = rr;
            int a = 0, q = 0;
            if (rr >= 0) {
                const int x = coords[3*rr], y = coords[3*rr+1], z = coords[3*rr+2];
                a = digit_of(x,y,z,7)*512 + digit_of(x,y,z,6)*64
                  + digit_of(x,y,z,5)*8 + digit_of(x,y,z,4);
                q = digit_of(x,y,z,2)*64 + digit_of(x,y,z,1)*8 + digit_of(x,y,z,0);
            }
            aidx[t] = a; qs[t] = q;
        }
        __syncthreads();

        // gather A (8 x 256) from P3 prefix rows: 512 f4, 2/thread
#pragma unroll
        for (int j = 0; j < 2; ++j) {
            const int idx = t + 256*j, s = idx >> 6, c4 = idx & 63;
            float4 v = make_float4(0,0,0,0);
            if (rows[s] >= 0)
                v = *(const float4*)(P3 + (size_t)aidx[s]*256 + c4*4);
            *(float4*)&Arm[s][c4*4] = v;
        }
        __syncthreads();                       // Arm ready (also drains prefetch)

        // main GEMM: wave wv accumulates all 8 rows over its own K range
        float4 acc[8];
#pragma unroll
        for (int r = 0; r < 8; ++r) acc[r] = make_float4(0,0,0,0);

#pragma unroll 1
        for (int s = 0; s < 16; ++s) {
            if (s < 15) {
                const int nb = (s + 1) & 1;
                const int ko = kbase + (s + 1) * 4;
#pragma unroll
                for (int j = 0; j < 4; ++j)
                    async_load16(Cd + (size_t)(ko + j)*2048 + ln*4,
                                 &Bs[wv][nb][j][ln*4]);
                asm volatile("s_waitcnt vmcnt(4)" ::: "memory");
            } else {
                asm volatile("s_waitcnt vmcnt(0)" ::: "memory");
            }
            __builtin_amdgcn_sched_barrier(0);
            const int cb = s & 1, kb = kbase + s * 4;
            const float4 b0v = *(const float4*)&Bs[wv][cb][0][ln*4];
            const float4 b1v = *(const float4*)&Bs[wv][cb][1][ln*4];
            const float4 b2v = *(const float4*)&Bs[wv][cb][2][ln*4];
            const float4 b3v = *(const float4*)&Bs[wv][cb][3][ln*4];
#pragma unroll
            for (int r = 0; r < 8; ++r) {
                const float4 a = *(const float4*)&Arm[r][kb];
                fma4(acc[r], a.x, b0v); fma4(acc[r], a.y, b1v);
                fma4(acc[r], a.z, b2v); fma4(acc[r], a.w, b3v);
            }
        }

        // cross-wave K reduction via dead Bs region
        {
            float* my = BsF + wv * 2048;
#pragma unroll
            for (int r = 0; r < 8; ++r)
                *(float4*)&my[r*256 + ln*4] = acc[r];
        }
        __syncthreads();

        // fused final: out[rr] = dot(V4row, T[q]); wave wv owns rows wv*2+{0,1}
#pragma unroll
        for (int i = 0; i < 2; ++i) {
            const int r = wv*2 + i;
            const int rr = rows[r];
            float p = 0.f;
            if (rr >= 0) {
                float4 v = *(const float4*)&BsF[       r*256 + ln*4];
                const float4 p1 = *(const float4*)&BsF[2048 + r*256 + ln*4];
                const float4 p2 = *(const float4*)&BsF[4096 + r*256 + ln*4];
                const float4 p3 = *(const float4*)&BsF[6144 + r*256 + ln*4];
                v.x += p1.x + p2.x + p3.x; v.y += p1.y + p2.y + p3.y;
                v.z += p1.z + p2.z + p3.z; v.w += p1.w + p2.w + p3.w;
                const float4 tv = *(const float4*)(T + (size_t)qs[r]*256 + ln*4);
                p = fmaf(v.x, tv.x, fmaf(v.y, tv.y, fmaf(v.z, tv.z, v.w * tv.w)));
            }
            p += __shfl_xor(p, 1);
            p += __shfl_xor(p, 2);
            p += __shfl_xor(p, 4);
            p += __shfl_xor(p, 8);
            p += __shfl_xor(p, 16);
            p += __shfl_xor(p, 32);
            if (ln == 0 && rr >= 0) out[rr] = p;
        }
        __syncthreads();   // protect rows/Arm/Bs before next tile's writes
    }
}

extern "C" void kernel_launch(void* const* d_in, const int* in_sizes, int n_in,
                              void* d_out, int out_size, void* d_ws, size_t ws_size,
                              hipStream_t stream) {
    const float* C0 = (const float*)d_in[0];
    const float* C1 = (const float*)d_in[1];
    const float* C2 = (const float*)d_in[2];
    const float* C3 = (const float*)d_in[3];
    const float* C4 = (const float*)d_in[4];
    const float* C5 = (const float*)d_in[5];
    const float* C6 = (const float*)d_in[6];
    const float* C7 = (const float*)d_in[7];
    const int* coords = (const int*)d_in[8];
    float* out = (float*)d_out;

    const int n = in_sizes[8] / 3;

    // workspace (~4.5 MB)
    float* P3   = (float*)d_ws;                       // 4096*256
    float* Tt   = P3 + 4096*256;                      // 512*256
    int*   perms = (int*)(Tt + 512*256);              // n
    int*   bases = perms + (size_t)n;                 // 9

    tables_kernel<<<577, 256, 0, stream>>>(
        C0, C1, C2, C3, C5, C6, C7, coords, n, perms, bases, P3, Tt);
    stage4_final_kernel<<<dim3(8, 64), 256, 0, stream>>>(
        P3, C4, Tt, coords, perms, bases, out);
}